// Round 6
// baseline (462.640 us; speedup 1.0000x reference)
//
#include <hip/hip_runtime.h>

#define NN 30000
#define NE 480000
#define NG 512
#define MAXD 48
#define BATCH 32
#define NB 938    // ceil(30000/32)
#define HPAD 144  // h_s row stride in shorts
#define NGB 469   // ceil(30000/64) for the 64-row GEMM kernels

typedef __attribute__((ext_vector_type(8))) short short8;
typedef __attribute__((ext_vector_type(4))) short s16x4;
typedef __attribute__((ext_vector_type(4))) float f32x4;

static __device__ __forceinline__ short f2bs(float f) {
  unsigned u = __builtin_bit_cast(unsigned, f);
  u = (u + 0x7fffu + ((u >> 16) & 1u)) >> 16;
  return (short)u;
}
static __device__ __forceinline__ float bs2f(short s) {
  unsigned u = ((unsigned)(unsigned short)s) << 16;
  return __builtin_bit_cast(float, u);
}
static __device__ __forceinline__ float sigf(float x) {
  return __builtin_amdgcn_rcpf(1.0f + __expf(-x));
}
static __device__ __forceinline__ float tanh_(float x) {
  return 1.0f - 2.0f * __builtin_amdgcn_rcpf(1.0f + __expf(2.0f * x));
}
// async 16B-per-lane gather into LDS: dest = ldsbase + lane*16
static __device__ __forceinline__ void gl_lds16(const short* g, short* l) {
  __builtin_amdgcn_global_load_lds(
      (const __attribute__((address_space(1))) void*)g,
      (__attribute__((address_space(3))) void*)l, 16, 0, 0);
}

// ---- prep: segment starts/ends via boundary detection (src sorted; no atomics)
__global__ void k_edges(const int* __restrict__ src, int* __restrict__ starts,
                        int* __restrict__ ends) {
  int e = blockIdx.x * 256 + threadIdx.x;
  if (e >= NE) return;
  int s = src[e];
  if (e == 0 || src[e - 1] != s) starts[s] = e;
  if (e == NE - 1 || src[e + 1] != s) ends[s] = e + 1;
}

// ---- degree histogram + descending-degree bucket offsets (one block) ----
__global__ void k_hs(const int* __restrict__ starts, const int* __restrict__ ends,
                     int* __restrict__ offs) {
  __shared__ int hist[MAXD + 1];
  int tid = threadIdx.x;
  if (tid <= MAXD) hist[tid] = 0;
  __syncthreads();
  for (int n = tid; n < NN; n += 1024) {
    int c = ends[n] - starts[n]; c = c > MAXD ? MAXD : c;
    atomicAdd(&hist[c], 1);
  }
  __syncthreads();
  if (tid == 0) {
    int total = 0;
    for (int b = MAXD; b >= 0; --b) { offs[b] = total; total += hist[b]; }
  }
}

__global__ void k_scatter(const int* __restrict__ starts, const int* __restrict__ ends,
                          int* __restrict__ offs, int* __restrict__ order) {
  int n = blockIdx.x * 256 + threadIdx.x;
  if (n >= NN) return;
  int c = ends[n] - starts[n]; c = c > MAXD ? MAXD : c;
  int slot = atomicAdd(&offs[c], 1);
  order[slot] = n;  // descending-degree permutation
}

__global__ void k_nbr(const int* __restrict__ src, const int* __restrict__ trg,
                      const int* __restrict__ starts, int* __restrict__ nbr) {
  int e = blockIdx.x * 256 + threadIdx.x;
  if (e >= NE) return;
  int s = src[e];
  int pos = e - starts[s];
  if (pos < MAXD) nbr[s * MAXD + pos] = trg[e];
}

// ---- proj = X @ W_ih.T + (b_ih+b_hh), bf16 MFMA, permuted layout:
// j = g*128 + wv*32 + db*16 + lc  ->  pos = (wv*16+lc)*8 + g*2 + db  ----
__global__ __launch_bounds__(256, 1) void k_proj(
    const float* __restrict__ x, const float* __restrict__ W_ih,
    const float* __restrict__ b_ih, const float* __restrict__ b_hh,
    short* __restrict__ proj) {
  __shared__ __align__(16) short xs[64 * HPAD];
  const int tid = threadIdx.x;
  const int wv = tid >> 6, lane = tid & 63, lq = lane >> 4, lc = lane & 15;
  const int base = blockIdx.x * 64;

  for (int idx4 = tid; idx4 < 64 * 32; idx4 += 256) {
    int row = idx4 >> 5, k4 = (idx4 & 31) << 2;
    f32x4 v = (f32x4){0.f, 0.f, 0.f, 0.f};
    if (base + row < NN) v = *(const f32x4*)&x[(base + row) * 128 + k4];
    s16x4 p; p[0] = f2bs(v[0]); p[1] = f2bs(v[1]); p[2] = f2bs(v[2]); p[3] = f2bs(v[3]);
    *(s16x4*)&xs[row * HPAD + k4] = p;
  }
  short8 wfrag[4][2][4];
#pragma unroll
  for (int g = 0; g < 4; ++g)
#pragma unroll
    for (int db = 0; db < 2; ++db)
#pragma unroll
      for (int kt = 0; kt < 4; ++kt) {
        const float* p =
            &W_ih[(g * 128 + wv * 32 + db * 16 + lc) * 128 + kt * 32 + lq * 8];
        f32x4 a = *(const f32x4*)p;
        f32x4 b = *(const f32x4*)(p + 4);
        short8 w;
        w[0] = f2bs(a[0]); w[1] = f2bs(a[1]); w[2] = f2bs(a[2]); w[3] = f2bs(a[3]);
        w[4] = f2bs(b[0]); w[5] = f2bs(b[1]); w[6] = f2bs(b[2]); w[7] = f2bs(b[3]);
        wfrag[g][db][kt] = w;
      }
  float bias_v[4][2];
#pragma unroll
  for (int g = 0; g < 4; ++g)
#pragma unroll
    for (int db = 0; db < 2; ++db) {
      int j = g * 128 + wv * 32 + db * 16 + lc;
      bias_v[g][db] = b_ih[j] + b_hh[j];
    }
  __syncthreads();

#pragma unroll
  for (int mt = 0; mt < 4; ++mt) {
    short8 afrag[4];
#pragma unroll
    for (int kt = 0; kt < 4; ++kt)
      afrag[kt] = *(const short8*)&xs[(mt * 16 + lc) * HPAD + kt * 32 + lq * 8];
    f32x4 acc[4][2];
#pragma unroll
    for (int g = 0; g < 4; ++g)
#pragma unroll
      for (int db = 0; db < 2; ++db) {
        float b = bias_v[g][db];
        acc[g][db] = (f32x4){b, b, b, b};
#pragma unroll
        for (int kt = 0; kt < 4; ++kt)
          acc[g][db] = __builtin_amdgcn_mfma_f32_16x16x32_bf16(
              afrag[kt], wfrag[g][db][kt], acc[g][db], 0, 0, 0);
      }
#pragma unroll
    for (int r = 0; r < 4; ++r) {
      int row = base + mt * 16 + lq * 4 + r;
      if (row < NN) {
        short8 w;
        w[0] = f2bs(acc[0][0][r]); w[1] = f2bs(acc[0][1][r]);
        w[2] = f2bs(acc[1][0][r]); w[3] = f2bs(acc[1][1][r]);
        w[4] = f2bs(acc[2][0][r]); w[5] = f2bs(acc[2][1][r]);
        w[6] = f2bs(acc[3][0][r]); w[7] = f2bs(acc[3][1][r]);
        *(short8*)&proj[row * NG + (wv * 16 + lc) * 8] = w;
      }
    }
  }
}

// ---- LSTM: W_hh B-frags register-resident; distance-1 prefetch of the proj
// gather via global_load_lds into a wave-private LDS buffer (no VGPR cost);
// double-buffered h_s with register copy-forward -> one barrier per step.
// launch_bounds (256,1): let the allocator take ~230 VGPRs; (256,2) made it
// pin 128 and spill ~105 MB/launch to scratch (r3-r5 WRITE_SIZE evidence). ----
__global__ __launch_bounds__(256, 1) void k_lstm(
    const float* __restrict__ W_hh, const short* __restrict__ proj,
    const int* __restrict__ order, const int* __restrict__ starts,
    const int* __restrict__ ends, const int* __restrict__ nbr,
    short* __restrict__ agg) {
  __shared__ __align__(16) short h_s[2][BATCH * HPAD];   // 18432 B
  __shared__ __align__(16) short pbuf[4][8][64 * 8];     // 32768 B, wave-private slots
  __shared__ unsigned short nbr_s[BATCH][MAXD];          // 3072 B
  __shared__ int nodes_s[BATCH];
  __shared__ int cnts_s[BATCH];

  const int tid = threadIdx.x;
  const int wv = tid >> 6, lane = tid & 63, lq = lane >> 4, lc = lane & 15;

  short8 wfrag[4][2][4];
#pragma unroll
  for (int g = 0; g < 4; ++g)
#pragma unroll
    for (int db = 0; db < 2; ++db)
#pragma unroll
      for (int kt = 0; kt < 4; ++kt) {
        const float* p =
            &W_hh[(g * 128 + wv * 32 + db * 16 + lc) * 128 + kt * 32 + lq * 8];
        f32x4 a = *(const f32x4*)p;
        f32x4 b = *(const f32x4*)(p + 4);
        short8 w;
        w[0] = f2bs(a[0]); w[1] = f2bs(a[1]); w[2] = f2bs(a[2]); w[3] = f2bs(a[3]);
        w[4] = f2bs(b[0]); w[5] = f2bs(b[1]); w[6] = f2bs(b[2]); w[7] = f2bs(b[3]);
        wfrag[g][db][kt] = w;
      }

  const int batch = blockIdx.x;
  if (tid < BATCH) {
    int gidx = batch * BATCH + tid;
    int node = 0, c = 0;
    if (gidx < NN) {
      node = order[gidx];
      c = ends[node] - starts[node]; c = c > MAXD ? MAXD : c;
    }
    nodes_s[tid] = node;
    cnts_s[tid] = c;
  }
  __syncthreads();
  for (int idx = tid; idx < BATCH * HPAD / 2; idx += 256)
    ((int*)h_s[0])[idx] = 0;
  for (int idx = tid; idx < BATCH * MAXD; idx += 256) {
    int m = idx / MAXD, p = idx - m * MAXD;
    nbr_s[m][p] = (unsigned short)nbr[nodes_s[m] * MAXD + p];
  }
  __syncthreads();
  const int T = cnts_s[0];  // descending sort -> batch max

  int cnt_v[2][4];
#pragma unroll
  for (int mt = 0; mt < 2; ++mt)
#pragma unroll
    for (int r = 0; r < 4; ++r) cnt_v[mt][r] = cnts_s[mt * 16 + lq * 4 + r];

  float c_v[2][2][4];
  s16x4 hvp[2][2];  // last-written h (bf16) for copy-forward of frozen rows
#pragma unroll
  for (int mt = 0; mt < 2; ++mt)
#pragma unroll
    for (int db = 0; db < 2; ++db) {
#pragma unroll
      for (int r = 0; r < 4; ++r) c_v[mt][db][r] = 0.0f;
      hvp[mt][db] = (s16x4){0, 0, 0, 0};
    }

  const int pcol = (wv * 16 + lc) * 8;
  if (T > 0) {  // prologue: async-gather t=0 slices into pbuf
#pragma unroll
    for (int mt = 0; mt < 2; ++mt)
#pragma unroll
      for (int r = 0; r < 4; ++r) {
        int m = mt * 16 + lq * 4 + r;
        int nb_i = (0 < cnt_v[mt][r]) ? (int)nbr_s[m][0] : 0;
        gl_lds16(&proj[nb_i * NG + pcol], &pbuf[wv][mt * 4 + r][0]);
      }
  }

  for (int t = 0; t < T; ++t) {
    __syncthreads();  // drains prefetch (vmcnt) + makes h writes visible
    const short* hb = h_s[t & 1];
    short* hw = h_s[(t + 1) & 1];
    const int tn = t + 1;
    const int ts = tn < MAXD ? tn : 0;
#pragma unroll
    for (int mt = 0; mt < 2; ++mt) {
      // consume this step's gathered slices (wave-private slots)
      short8 pv[4];
#pragma unroll
      for (int r = 0; r < 4; ++r)
        pv[r] = *(const short8*)&pbuf[wv][mt * 4 + r][lane * 8];
      f32x4 acc[4][2];
#pragma unroll
      for (int g = 0; g < 4; ++g)
#pragma unroll
        for (int db = 0; db < 2; ++db)
#pragma unroll
          for (int r = 0; r < 4; ++r)
            acc[g][db][r] = bs2f(pv[r][g * 2 + db]);  // x-part + bias
      __builtin_amdgcn_sched_barrier(0);  // pv fully consumed before overwrite
      if (tn < T) {  // prefetch t+1 into the same (now free) slots
#pragma unroll
        for (int r = 0; r < 4; ++r) {
          int m = mt * 16 + lq * 4 + r;
          int nb_i = (tn < cnt_v[mt][r]) ? (int)nbr_s[m][ts] : 0;
          gl_lds16(&proj[nb_i * NG + pcol], &pbuf[wv][mt * 4 + r][0]);
        }
      }
      __builtin_amdgcn_sched_barrier(0);  // keep prefetch issue early
      short8 afrag[4];
#pragma unroll
      for (int kt = 0; kt < 4; ++kt)
        afrag[kt] = *(const short8*)&hb[(mt * 16 + lc) * HPAD + kt * 32 + lq * 8];
#pragma unroll
      for (int g = 0; g < 4; ++g)
#pragma unroll
        for (int db = 0; db < 2; ++db)
#pragma unroll
          for (int kt = 0; kt < 4; ++kt)
            acc[g][db] = __builtin_amdgcn_mfma_f32_16x16x32_bf16(
                afrag[kt], wfrag[g][db][kt], acc[g][db], 0, 0, 0);
#pragma unroll
      for (int db = 0; db < 2; ++db)
#pragma unroll
        for (int r = 0; r < 4; ++r) {
          float iv = sigf(acc[0][db][r]);
          float fv = sigf(acc[1][db][r]);
          float gv = tanh_(acc[2][db][r]);
          float ov = sigf(acc[3][db][r]);
          float c2 = fv * c_v[mt][db][r] + iv * gv;
          float h2 = ov * tanh_(c2);
          if (t < cnt_v[mt][r]) {
            c_v[mt][db][r] = c2;
            hvp[mt][db][r] = f2bs(h2);
          }
        }
      // unconditional write of (new or carried) h into the other buffer
#pragma unroll
      for (int db = 0; db < 2; ++db)
#pragma unroll
        for (int r = 0; r < 4; ++r)
          hw[(mt * 16 + lq * 4 + r) * HPAD + wv * 32 + db * 16 + lc] =
              hvp[mt][db][r];
    }
  }
  __syncthreads();  // last step's h writes visible
  const short* hf = h_s[T & 1];
  for (int idx = tid; idx < BATCH * 128; idx += 256) {
    int m = idx >> 7, d = idx & 127;
    if (batch * BATCH + m < NN) agg[nodes_s[m] * 128 + d] = hf[m * HPAD + d];
  }
}

// ---- out = [x | h] @ W_out, bf16 MFMA ----
__global__ __launch_bounds__(256, 2) void k_out(
    const float* __restrict__ x, const short* __restrict__ agg,
    const float* __restrict__ Wout, float* __restrict__ out) {
  __shared__ __align__(16) short xs[64 * 272];
  const int tid = threadIdx.x;
  const int wv = tid >> 6, lane = tid & 63, lq = lane >> 4, lc = lane & 15;
  const int base = blockIdx.x * 64;

  for (int idx4 = tid; idx4 < 64 * 32; idx4 += 256) {
    int row = idx4 >> 5, k4 = (idx4 & 31) << 2;
    f32x4 v = (f32x4){0.f, 0.f, 0.f, 0.f};
    if (base + row < NN) v = *(const f32x4*)&x[(base + row) * 128 + k4];
    s16x4 p; p[0] = f2bs(v[0]); p[1] = f2bs(v[1]); p[2] = f2bs(v[2]); p[3] = f2bs(v[3]);
    *(s16x4*)&xs[row * 272 + k4] = p;
    s16x4 a = (s16x4){0, 0, 0, 0};
    if (base + row < NN) a = *(const s16x4*)&agg[(base + row) * 128 + k4];
    *(s16x4*)&xs[row * 272 + 128 + k4] = a;
  }
  short8 wf[2][8];
#pragma unroll
  for (int db = 0; db < 2; ++db)
#pragma unroll
    for (int kt = 0; kt < 8; ++kt) {
      short8 w;
#pragma unroll
      for (int jj = 0; jj < 8; ++jj)
        w[jj] = f2bs(Wout[(kt * 32 + lq * 8 + jj) * 128 + wv * 32 + db * 16 + lc]);
      wf[db][kt] = w;
    }
  __syncthreads();

#pragma unroll
  for (int mt = 0; mt < 4; ++mt) {
    short8 afrag[8];
#pragma unroll
    for (int kt = 0; kt < 8; ++kt)
      afrag[kt] = *(const short8*)&xs[(mt * 16 + lc) * 272 + kt * 32 + lq * 8];
    f32x4 acc[2];
#pragma unroll
    for (int db = 0; db < 2; ++db) {
      acc[db] = (f32x4){0.f, 0.f, 0.f, 0.f};
#pragma unroll
      for (int kt = 0; kt < 8; ++kt)
        acc[db] = __builtin_amdgcn_mfma_f32_16x16x32_bf16(
            afrag[kt], wf[db][kt], acc[db], 0, 0, 0);
    }
#pragma unroll
    for (int db = 0; db < 2; ++db)
#pragma unroll
      for (int r = 0; r < 4; ++r) {
        int row = base + mt * 16 + lq * 4 + r;
        if (row < NN)
          out[row * 128 + wv * 32 + db * 16 + lc] = acc[db][r];
      }
  }
}

extern "C" void kernel_launch(void* const* d_in, const int* in_sizes, int n_in,
                              void* d_out, int out_size, void* d_ws,
                              size_t ws_size, hipStream_t stream) {
  (void)in_sizes; (void)n_in; (void)out_size; (void)ws_size;
  const float* x     = (const float*)d_in[0];
  const float* W_ih  = (const float*)d_in[1];
  const float* W_hh  = (const float*)d_in[2];
  const float* b_ih  = (const float*)d_in[3];
  const float* b_hh  = (const float*)d_in[4];
  const float* W_out = (const float*)d_in[5];
  const int*   esrc  = (const int*)d_in[6];
  const int*   etrg  = (const int*)d_in[7];
  float* out = (float*)d_out;
  char* ws = (char*)d_ws;

  int*   starts = (int*)(ws + 0);          // 120000 B
  int*   ends   = (int*)(ws + 120064);     // 120000 B
  int*   offs   = (int*)(ws + 240128);     // 196 B
  int*   order  = (int*)(ws + 240384);     // 120000 B
  int*   nbr    = (int*)(ws + 360448);     // 5,760,000 B
  short* proj   = (short*)(ws + 6382848);  // 30,720,000 B (bf16, permuted cols)
  short* agg    = (short*)(ws + 37102848); // 7,680,000 B (bf16)

  (void)hipMemsetAsync(d_ws, 0, 240128, stream);  // starts + ends

  k_edges  <<<1875, 256, 0, stream>>>(esrc, starts, ends);
  k_hs     <<<1, 1024, 0, stream>>>(starts, ends, offs);
  k_scatter<<<118, 256, 0, stream>>>(starts, ends, offs, order);
  k_nbr    <<<1875, 256, 0, stream>>>(esrc, etrg, starts, nbr);
  k_proj   <<<NGB, 256, 0, stream>>>(x, W_ih, b_ih, b_hh, proj);
  k_lstm   <<<NB, 256, 0, stream>>>(W_hh, proj, order, starts, ends, nbr, agg);
  k_out    <<<NGB, 256, 0, stream>>>(x, agg, W_out, out);
}

// Round 7
// 416.336 us; speedup vs baseline: 1.1112x; 1.1112x over previous
//
#include <hip/hip_runtime.h>

#define NN 30000
#define NE 480000
#define NG 512
#define MAXD 48
#define BATCH 32
#define NB 938    // ceil(30000/32)
#define HPAD 144  // h_s row stride in shorts
#define NGB 469   // ceil(30000/64) for the 64-row GEMM kernels

typedef __attribute__((ext_vector_type(8))) short short8;
typedef __attribute__((ext_vector_type(4))) short s16x4;
typedef __attribute__((ext_vector_type(4))) float f32x4;

static __device__ __forceinline__ short f2bs(float f) {
  unsigned u = __builtin_bit_cast(unsigned, f);
  u = (u + 0x7fffu + ((u >> 16) & 1u)) >> 16;
  return (short)u;
}
static __device__ __forceinline__ float bs2f(short s) {
  unsigned u = ((unsigned)(unsigned short)s) << 16;
  return __builtin_bit_cast(float, u);
}
static __device__ __forceinline__ float sigf(float x) {
  return __builtin_amdgcn_rcpf(1.0f + __expf(-x));
}
static __device__ __forceinline__ float tanh_(float x) {
  return 1.0f - 2.0f * __builtin_amdgcn_rcpf(1.0f + __expf(2.0f * x));
}
// async 16B-per-lane gather into LDS: dest = ldsbase + lane*16
static __device__ __forceinline__ void gl_lds16(const short* g, short* l) {
  __builtin_amdgcn_global_load_lds(
      (const __attribute__((address_space(1))) void*)g,
      (__attribute__((address_space(3))) void*)l, 16, 0, 0);
}

// ---- prep: segment starts/ends via boundary detection (src sorted; no atomics)
__global__ void k_edges(const int* __restrict__ src, int* __restrict__ starts,
                        int* __restrict__ ends) {
  int e = blockIdx.x * 256 + threadIdx.x;
  if (e >= NE) return;
  int s = src[e];
  if (e == 0 || src[e - 1] != s) starts[s] = e;
  if (e == NE - 1 || src[e + 1] != s) ends[s] = e + 1;
}

// ---- degree histogram + descending-degree bucket offsets (one block) ----
__global__ void k_hs(const int* __restrict__ starts, const int* __restrict__ ends,
                     int* __restrict__ offs) {
  __shared__ int hist[MAXD + 1];
  int tid = threadIdx.x;
  if (tid <= MAXD) hist[tid] = 0;
  __syncthreads();
  for (int n = tid; n < NN; n += 1024) {
    int c = ends[n] - starts[n]; c = c > MAXD ? MAXD : c;
    atomicAdd(&hist[c], 1);
  }
  __syncthreads();
  if (tid == 0) {
    int total = 0;
    for (int b = MAXD; b >= 0; --b) { offs[b] = total; total += hist[b]; }
  }
}

__global__ void k_scatter(const int* __restrict__ starts, const int* __restrict__ ends,
                          int* __restrict__ offs, int* __restrict__ order) {
  int n = blockIdx.x * 256 + threadIdx.x;
  if (n >= NN) return;
  int c = ends[n] - starts[n]; c = c > MAXD ? MAXD : c;
  int slot = atomicAdd(&offs[c], 1);
  order[slot] = n;  // descending-degree permutation
}

__global__ void k_nbr(const int* __restrict__ src, const int* __restrict__ trg,
                      const int* __restrict__ starts, int* __restrict__ nbr) {
  int e = blockIdx.x * 256 + threadIdx.x;
  if (e >= NE) return;
  int s = src[e];
  int pos = e - starts[s];
  if (pos < MAXD) nbr[s * MAXD + pos] = trg[e];
}

// ---- proj = X @ W_ih.T + (b_ih+b_hh), bf16 MFMA, permuted layout:
// j = g*128 + wv*32 + db*16 + lc  ->  pos = (wv*16+lc)*8 + g*2 + db  ----
__global__ __launch_bounds__(256)
__attribute__((amdgpu_waves_per_eu(2, 2))) void k_proj(
    const float* __restrict__ x, const float* __restrict__ W_ih,
    const float* __restrict__ b_ih, const float* __restrict__ b_hh,
    short* __restrict__ proj) {
  __shared__ __align__(16) short xs[64 * HPAD];
  const int tid = threadIdx.x;
  const int wv = tid >> 6, lane = tid & 63, lq = lane >> 4, lc = lane & 15;
  const int base = blockIdx.x * 64;

  for (int idx4 = tid; idx4 < 64 * 32; idx4 += 256) {
    int row = idx4 >> 5, k4 = (idx4 & 31) << 2;
    f32x4 v = (f32x4){0.f, 0.f, 0.f, 0.f};
    if (base + row < NN) v = *(const f32x4*)&x[(base + row) * 128 + k4];
    s16x4 p; p[0] = f2bs(v[0]); p[1] = f2bs(v[1]); p[2] = f2bs(v[2]); p[3] = f2bs(v[3]);
    *(s16x4*)&xs[row * HPAD + k4] = p;
  }
  short8 wfrag[4][2][4];
#pragma unroll
  for (int g = 0; g < 4; ++g)
#pragma unroll
    for (int db = 0; db < 2; ++db)
#pragma unroll
      for (int kt = 0; kt < 4; ++kt) {
        const float* p =
            &W_ih[(g * 128 + wv * 32 + db * 16 + lc) * 128 + kt * 32 + lq * 8];
        f32x4 a = *(const f32x4*)p;
        f32x4 b = *(const f32x4*)(p + 4);
        short8 w;
        w[0] = f2bs(a[0]); w[1] = f2bs(a[1]); w[2] = f2bs(a[2]); w[3] = f2bs(a[3]);
        w[4] = f2bs(b[0]); w[5] = f2bs(b[1]); w[6] = f2bs(b[2]); w[7] = f2bs(b[3]);
        wfrag[g][db][kt] = w;
      }
  float bias_v[4][2];
#pragma unroll
  for (int g = 0; g < 4; ++g)
#pragma unroll
    for (int db = 0; db < 2; ++db) {
      int j = g * 128 + wv * 32 + db * 16 + lc;
      bias_v[g][db] = b_ih[j] + b_hh[j];
    }
  __syncthreads();

#pragma unroll
  for (int mt = 0; mt < 4; ++mt) {
    short8 afrag[4];
#pragma unroll
    for (int kt = 0; kt < 4; ++kt)
      afrag[kt] = *(const short8*)&xs[(mt * 16 + lc) * HPAD + kt * 32 + lq * 8];
    f32x4 acc[4][2];
#pragma unroll
    for (int g = 0; g < 4; ++g)
#pragma unroll
      for (int db = 0; db < 2; ++db) {
        float b = bias_v[g][db];
        acc[g][db] = (f32x4){b, b, b, b};
#pragma unroll
        for (int kt = 0; kt < 4; ++kt)
          acc[g][db] = __builtin_amdgcn_mfma_f32_16x16x32_bf16(
              afrag[kt], wfrag[g][db][kt], acc[g][db], 0, 0, 0);
      }
#pragma unroll
    for (int r = 0; r < 4; ++r) {
      int row = base + mt * 16 + lq * 4 + r;
      if (row < NN) {
        short8 w;
        w[0] = f2bs(acc[0][0][r]); w[1] = f2bs(acc[0][1][r]);
        w[2] = f2bs(acc[1][0][r]); w[3] = f2bs(acc[1][1][r]);
        w[4] = f2bs(acc[2][0][r]); w[5] = f2bs(acc[2][1][r]);
        w[6] = f2bs(acc[3][0][r]); w[7] = f2bs(acc[3][1][r]);
        *(short8*)&proj[row * NG + (wv * 16 + lc) * 8] = w;
      }
    }
  }
}

// ---- LSTM: W_hh B-frags register-resident; distance-1 prefetch of the proj
// gather via global_load_lds into a wave-private LDS buffer; double-buffered
// h_s with register copy-forward -> one barrier per step.
// waves_per_eu(2,2): exact 256-reg total budget. (256,1) let the allocator
// exceed 256 total (1 wave/SIMD, r6); (256,2) made it compress to 128 arch
// and spill 105 MB (r5). Counts packed 4-per-int to shave VGPRs. ----
__global__ __launch_bounds__(256)
__attribute__((amdgpu_waves_per_eu(2, 2))) void k_lstm(
    const float* __restrict__ W_hh, const short* __restrict__ proj,
    const int* __restrict__ order, const int* __restrict__ starts,
    const int* __restrict__ ends, const int* __restrict__ nbr,
    short* __restrict__ agg) {
  __shared__ __align__(16) short h_s[2][BATCH * HPAD];   // 18432 B
  __shared__ __align__(16) short pbuf[4][8][64 * 8];     // 32768 B, wave-private slots
  __shared__ unsigned short nbr_s[BATCH][MAXD];          // 3072 B
  __shared__ int nodes_s[BATCH];
  __shared__ int cnts_s[BATCH];

  const int tid = threadIdx.x;
  const int wv = tid >> 6, lane = tid & 63, lq = lane >> 4, lc = lane & 15;

  short8 wfrag[4][2][4];
#pragma unroll
  for (int g = 0; g < 4; ++g)
#pragma unroll
    for (int db = 0; db < 2; ++db)
#pragma unroll
      for (int kt = 0; kt < 4; ++kt) {
        const float* p =
            &W_hh[(g * 128 + wv * 32 + db * 16 + lc) * 128 + kt * 32 + lq * 8];
        f32x4 a = *(const f32x4*)p;
        f32x4 b = *(const f32x4*)(p + 4);
        short8 w;
        w[0] = f2bs(a[0]); w[1] = f2bs(a[1]); w[2] = f2bs(a[2]); w[3] = f2bs(a[3]);
        w[4] = f2bs(b[0]); w[5] = f2bs(b[1]); w[6] = f2bs(b[2]); w[7] = f2bs(b[3]);
        wfrag[g][db][kt] = w;
      }

  const int batch = blockIdx.x;
  if (tid < BATCH) {
    int gidx = batch * BATCH + tid;
    int node = 0, c = 0;
    if (gidx < NN) {
      node = order[gidx];
      c = ends[node] - starts[node]; c = c > MAXD ? MAXD : c;
    }
    nodes_s[tid] = node;
    cnts_s[tid] = c;
  }
  __syncthreads();
  for (int idx = tid; idx < BATCH * HPAD / 2; idx += 256)
    ((int*)h_s[0])[idx] = 0;
  for (int idx = tid; idx < BATCH * MAXD; idx += 256) {
    int m = idx / MAXD, p = idx - m * MAXD;
    nbr_s[m][p] = (unsigned short)nbr[nodes_s[m] * MAXD + p];
  }
  __syncthreads();
  const int T = cnts_s[0];  // descending sort -> batch max

  // counts packed 4-per-int (each <= 48 fits in 8 bits)
  int cp[2];
#pragma unroll
  for (int mt = 0; mt < 2; ++mt) {
    int p = 0;
#pragma unroll
    for (int r = 0; r < 4; ++r) p |= cnts_s[mt * 16 + lq * 4 + r] << (r * 8);
    cp[mt] = p;
  }

  float c_v[2][2][4];
  s16x4 hvp[2][2];  // last-written h (bf16) for copy-forward of frozen rows
#pragma unroll
  for (int mt = 0; mt < 2; ++mt)
#pragma unroll
    for (int db = 0; db < 2; ++db) {
#pragma unroll
      for (int r = 0; r < 4; ++r) c_v[mt][db][r] = 0.0f;
      hvp[mt][db] = (s16x4){0, 0, 0, 0};
    }

  const int pcol = (wv * 16 + lc) * 8;
  if (T > 0) {  // prologue: async-gather t=0 slices into pbuf
#pragma unroll
    for (int mt = 0; mt < 2; ++mt)
#pragma unroll
      for (int r = 0; r < 4; ++r) {
        int m = mt * 16 + lq * 4 + r;
        int nb_i = (0 < ((cp[mt] >> (r * 8)) & 255)) ? (int)nbr_s[m][0] : 0;
        gl_lds16(&proj[nb_i * NG + pcol], &pbuf[wv][mt * 4 + r][0]);
      }
  }

  for (int t = 0; t < T; ++t) {
    __syncthreads();  // drains prefetch (vmcnt) + makes h writes visible
    const short* hb = h_s[t & 1];
    short* hw = h_s[(t + 1) & 1];
    const int tn = t + 1;
    const int ts = tn < MAXD ? tn : 0;
#pragma unroll
    for (int mt = 0; mt < 2; ++mt) {
      // consume this step's gathered slices (wave-private slots)
      short8 pv[4];
#pragma unroll
      for (int r = 0; r < 4; ++r)
        pv[r] = *(const short8*)&pbuf[wv][mt * 4 + r][lane * 8];
      f32x4 acc[4][2];
#pragma unroll
      for (int g = 0; g < 4; ++g)
#pragma unroll
        for (int db = 0; db < 2; ++db)
#pragma unroll
          for (int r = 0; r < 4; ++r)
            acc[g][db][r] = bs2f(pv[r][g * 2 + db]);  // x-part + bias
      __builtin_amdgcn_sched_barrier(0);  // pv fully consumed before overwrite
      if (tn < T) {  // prefetch t+1 into the same (now free) slots
#pragma unroll
        for (int r = 0; r < 4; ++r) {
          int m = mt * 16 + lq * 4 + r;
          int nb_i = (tn < ((cp[mt] >> (r * 8)) & 255)) ? (int)nbr_s[m][ts] : 0;
          gl_lds16(&proj[nb_i * NG + pcol], &pbuf[wv][mt * 4 + r][0]);
        }
      }
      __builtin_amdgcn_sched_barrier(0);  // keep prefetch issue early
      short8 afrag[4];
#pragma unroll
      for (int kt = 0; kt < 4; ++kt)
        afrag[kt] = *(const short8*)&hb[(mt * 16 + lc) * HPAD + kt * 32 + lq * 8];
#pragma unroll
      for (int g = 0; g < 4; ++g)
#pragma unroll
        for (int db = 0; db < 2; ++db)
#pragma unroll
          for (int kt = 0; kt < 4; ++kt)
            acc[g][db] = __builtin_amdgcn_mfma_f32_16x16x32_bf16(
                afrag[kt], wfrag[g][db][kt], acc[g][db], 0, 0, 0);
#pragma unroll
      for (int db = 0; db < 2; ++db)
#pragma unroll
        for (int r = 0; r < 4; ++r) {
          float iv = sigf(acc[0][db][r]);
          float fv = sigf(acc[1][db][r]);
          float gv = tanh_(acc[2][db][r]);
          float ov = sigf(acc[3][db][r]);
          float c2 = fv * c_v[mt][db][r] + iv * gv;
          float h2 = ov * tanh_(c2);
          if (t < ((cp[mt] >> (r * 8)) & 255)) {
            c_v[mt][db][r] = c2;
            hvp[mt][db][r] = f2bs(h2);
          }
        }
      // unconditional write of (new or carried) h into the other buffer
#pragma unroll
      for (int db = 0; db < 2; ++db)
#pragma unroll
        for (int r = 0; r < 4; ++r)
          hw[(mt * 16 + lq * 4 + r) * HPAD + wv * 32 + db * 16 + lc] =
              hvp[mt][db][r];
    }
  }
  __syncthreads();  // last step's h writes visible
  const short* hf = h_s[T & 1];
  for (int idx = tid; idx < BATCH * 128; idx += 256) {
    int m = idx >> 7, d = idx & 127;
    if (batch * BATCH + m < NN) agg[nodes_s[m] * 128 + d] = hf[m * HPAD + d];
  }
}

// ---- out = [x | h] @ W_out, bf16 MFMA ----
__global__ __launch_bounds__(256, 2) void k_out(
    const float* __restrict__ x, const short* __restrict__ agg,
    const float* __restrict__ Wout, float* __restrict__ out) {
  __shared__ __align__(16) short xs[64 * 272];
  const int tid = threadIdx.x;
  const int wv = tid >> 6, lane = tid & 63, lq = lane >> 4, lc = lane & 15;
  const int base = blockIdx.x * 64;

  for (int idx4 = tid; idx4 < 64 * 32; idx4 += 256) {
    int row = idx4 >> 5, k4 = (idx4 & 31) << 2;
    f32x4 v = (f32x4){0.f, 0.f, 0.f, 0.f};
    if (base + row < NN) v = *(const f32x4*)&x[(base + row) * 128 + k4];
    s16x4 p; p[0] = f2bs(v[0]); p[1] = f2bs(v[1]); p[2] = f2bs(v[2]); p[3] = f2bs(v[3]);
    *(s16x4*)&xs[row * 272 + k4] = p;
    s16x4 a = (s16x4){0, 0, 0, 0};
    if (base + row < NN) a = *(const s16x4*)&agg[(base + row) * 128 + k4];
    *(s16x4*)&xs[row * 272 + 128 + k4] = a;
  }
  short8 wf[2][8];
#pragma unroll
  for (int db = 0; db < 2; ++db)
#pragma unroll
    for (int kt = 0; kt < 8; ++kt) {
      short8 w;
#pragma unroll
      for (int jj = 0; jj < 8; ++jj)
        w[jj] = f2bs(Wout[(kt * 32 + lq * 8 + jj) * 128 + wv * 32 + db * 16 + lc]);
      wf[db][kt] = w;
    }
  __syncthreads();

#pragma unroll
  for (int mt = 0; mt < 4; ++mt) {
    short8 afrag[8];
#pragma unroll
    for (int kt = 0; kt < 8; ++kt)
      afrag[kt] = *(const short8*)&xs[(mt * 16 + lc) * 272 + kt * 32 + lq * 8];
    f32x4 acc[2];
#pragma unroll
    for (int db = 0; db < 2; ++db) {
      acc[db] = (f32x4){0.f, 0.f, 0.f, 0.f};
#pragma unroll
      for (int kt = 0; kt < 8; ++kt)
        acc[db] = __builtin_amdgcn_mfma_f32_16x16x32_bf16(
            afrag[kt], wf[db][kt], acc[db], 0, 0, 0);
    }
#pragma unroll
    for (int db = 0; db < 2; ++db)
#pragma unroll
      for (int r = 0; r < 4; ++r) {
        int row = base + mt * 16 + lq * 4 + r;
        if (row < NN)
          out[row * 128 + wv * 32 + db * 16 + lc] = acc[db][r];
      }
  }
}

extern "C" void kernel_launch(void* const* d_in, const int* in_sizes, int n_in,
                              void* d_out, int out_size, void* d_ws,
                              size_t ws_size, hipStream_t stream) {
  (void)in_sizes; (void)n_in; (void)out_size; (void)ws_size;
  const float* x     = (const float*)d_in[0];
  const float* W_ih  = (const float*)d_in[1];
  const float* W_hh  = (const float*)d_in[2];
  const float* b_ih  = (const float*)d_in[3];
  const float* b_hh  = (const float*)d_in[4];
  const float* W_out = (const float*)d_in[5];
  const int*   esrc  = (const int*)d_in[6];
  const int*   etrg  = (const int*)d_in[7];
  float* out = (float*)d_out;
  char* ws = (char*)d_ws;

  int*   starts = (int*)(ws + 0);          // 120000 B
  int*   ends   = (int*)(ws + 120064);     // 120000 B
  int*   offs   = (int*)(ws + 240128);     // 196 B
  int*   order  = (int*)(ws + 240384);     // 120000 B
  int*   nbr    = (int*)(ws + 360448);     // 5,760,000 B
  short* proj   = (short*)(ws + 6382848);  // 30,720,000 B (bf16, permuted cols)
  short* agg    = (short*)(ws + 37102848); // 7,680,000 B (bf16)

  (void)hipMemsetAsync(d_ws, 0, 240128, stream);  // starts + ends

  k_edges  <<<1875, 256, 0, stream>>>(esrc, starts, ends);
  k_hs     <<<1, 1024, 0, stream>>>(starts, ends, offs);
  k_scatter<<<118, 256, 0, stream>>>(starts, ends, offs, order);
  k_nbr    <<<1875, 256, 0, stream>>>(esrc, etrg, starts, nbr);
  k_proj   <<<NGB, 256, 0, stream>>>(x, W_ih, b_ih, b_hh, proj);
  k_lstm   <<<NB, 256, 0, stream>>>(W_hh, proj, order, starts, ends, nbr, agg);
  k_out    <<<NGB, 256, 0, stream>>>(x, agg, W_out, out);
}